// Round 6
// baseline (1654.863 us; speedup 1.0000x reference)
//
#include <hip/hip_runtime.h>

// CharNNClassifier: out = (LSTM(emb[x]) last h) @ W_out^T + b_out
// B=256 S=512 V=256 E=128 H=256 4H=1024 O=128, fp32 in/out.
//
// R9 = R8 with the per-step overhead attacked (MFMA floor is ~2-2.5k cyc
// and invariant; measured step was 4.8k).
//  R8 post-mortem: spill fixed (WRITE 27.6->5.8 MB) but time ~flat ->
//  critical path is waits: 2x bounce lgkmcnt(0) stalls/step + 512
//  conflict-cycles/CU-step (hbuf 528B row stride aliases A-reads vs
//  zbuf broadcasts) + barrier.
//  R9 changes:
//   - single bounce stall: pass0 MFMAs -> ds_write acc -> pass1 MFMAs ->
//     ds_write -> ONE lgkmcnt(0) -> read all 8 slots (b64 row-pairs).
//     acc[4] regs still reused across passes (writes consume at issue).
//   - hbuf HSTRIDE 272 (rows at bank phase 0/8/16/24): A-read aliasing
//     becomes uniform 2-way (free). zbuf separate for pad rows.
//   - bounce rows 160 B apart, 8 slots, 3-bit XOR swizzle (l15&7)<<4:
//     writes 2-way uniform.
//  W_hh split (proven): kt0..1 LDS 128 KB, kt2..5 wreg 128 VGPR,
//  kt6..7 streamed per pass from prepacked Wpk (K1b).
//  LDS = 128K wlds + 4.25K hbuf + 20K sc + 0.5K zbuf = 152.75 KB.

typedef _Float16 f16x8 __attribute__((ext_vector_type(8)));
typedef _Float16 f16x4 __attribute__((ext_vector_type(4)));
typedef float    f32x4 __attribute__((ext_vector_type(4)));
typedef float    f32x2 __attribute__((ext_vector_type(2)));

#define B_  256
#define S_  512
#define V_  256
#define E_  128
#define H_  256
#define O_  128

// ws layout (bytes)
#define T_OFF     0u              // T2h: 256*256*4 fp16 = 512 KiB
#define HLAST_OFF (512u << 10)    // hlast: 256*256*4B   = 256 KiB
#define WPK_OFF   (768u << 10)    // Wpk: 16*512*16B     = 128 KiB

// ---------------------------------------------------------------- K1: table
// T2h[v][unit] = fp16x4 {i,f,g,o} pre-activations from the embedding path.
__global__ void build_table(const float* __restrict__ emb,
                            const float* __restrict__ W_ih,
                            const float* __restrict__ b_ih,
                            const float* __restrict__ b_hh,
                            _Float16* __restrict__ T2h) {
    const int v   = blockIdx.x;   // vocab id
    const int tid = threadIdx.x;  // 256 threads = hidden unit

    __shared__ float e[E_];
    if (tid < E_) e[tid] = emb[v * E_ + tid];
    __syncthreads();

    f16x4 tv;
#pragma unroll
    for (int t = 0; t < 4; ++t) {
        const int g = t * 256 + tid;
        const float4* wp = (const float4*)(W_ih + g * E_);
        float acc = 0.f;
#pragma unroll
        for (int i = 0; i < E_ / 4; ++i) {
            float4 w = wp[i];
            acc += w.x * e[4*i] + w.y * e[4*i+1] + w.z * e[4*i+2] + w.w * e[4*i+3];
        }
        tv[t] = (_Float16)(acc + b_ih[g] + b_hh[g]);
    }
    *(f16x4*)(T2h + ((size_t)v * 256 + tid) * 4) = tv;
}

// ------------------------------------------------------- K1b: W-frag prepack
// Wpk[blk=ktS*8+j][tid] = the f16x8 B-fragment thread tid needs for
// (kt = 6+ktS, j). Lane math mirrors the main kernel's prologue.
__global__ void prepack(const float* __restrict__ W_hh,
                        _Float16* __restrict__ Wpk) {
    const int blk = blockIdx.x;      // 0..15 = ktS*8 + j
    const int ktS = blk >> 3;
    const int j   = blk & 7;
    const int kt  = 6 + ktS;
    const int tid = threadIdx.x;     // 512
    const int wv = tid >> 6, l = tid & 63, l15 = l & 15, quad = l >> 4;
    const int n  = j * 128 + wv * 16 + l15;   // gate column
    const int k0 = kt * 32 + quad * 8;
    const float4* wp = (const float4*)(W_hh + (size_t)n * H_ + k0);
    float4 w0 = wp[0];
    float4 w1 = wp[1];
    f16x8 f = (f16x8){
        (_Float16)w0.x, (_Float16)w0.y, (_Float16)w0.z, (_Float16)w0.w,
        (_Float16)w1.x, (_Float16)w1.y, (_Float16)w1.z, (_Float16)w1.w};
    *(f16x8*)(Wpk + ((size_t)blk * 512 + tid) * 8) = f;
}

// ------------------------------------------------------------ K2: recurrence
// Pre-act bounds: |W_hh row . h| <= 256*(1/16) = 16 hard; |table| < ~5.
// Sigmoid needs no clamp; tanh keeps a +-30 clamp as overflow insurance.
__device__ __forceinline__ float sig_fast(float x) {
    float t = __builtin_amdgcn_exp2f(-1.4426950408889634f * x);
    return __builtin_amdgcn_rcpf(1.f + t);
}
__device__ __forceinline__ float tanh_fast(float x) {
    x = fminf(fmaxf(x, -30.f), 30.f);
    float t = __builtin_amdgcn_exp2f(-2.8853900817779268f * x);  // e^{-2x}
    return (1.f - t) * __builtin_amdgcn_rcpf(1.f + t);
}

#define HSTRIDE 272   // fp16/row: 544 B => row bank-phase 0/8/16/24

__launch_bounds__(512, 2)
__global__ void lstm_persistent(const int* __restrict__ x,
                                const float* __restrict__ W_hh,
                                const _Float16* __restrict__ T2h,
                                const _Float16* __restrict__ Wpk,
                                float* __restrict__ hlast) {
    const int tid    = threadIdx.x;
    const int wv     = tid >> 6;     // wave 0..7
    const int l      = tid & 63;
    const int l15    = l & 15;
    const int quad   = l >> 4;       // 0..3
    const int stripe = blockIdx.x;   // batch rows [stripe*4, +4)

    // LDS: 128 KB weights (kt 0..1) + h dbuf + 8-slot bounce + zero block.
    __shared__ __align__(16) _Float16 wlds[8][8][2][512];   // 128 KiB
    __shared__ __align__(16) _Float16 hbuf[2][4][HSTRIDE];  // 4.25 KiB
    __shared__ __align__(16) float    sc[8][16][40];        //  20 KiB
    __shared__ __align__(16) _Float16 zbuf[256];            // 512 B zeros

    if (tid < 128) ((int*)zbuf)[tid] = 0;

    // ---- prologue: kt 0..5 of W_hh -> fp16 B-frags (kt 0..1 LDS, 2..5 reg)
    // col n = j*128 + wv*16 + l15; k = kt*32 + quad*8 + i; B[k][n] = W_hh[n][k]
    f16x8 wreg[8][4];
#pragma unroll
    for (int j = 0; j < 8; ++j) {
        const float* wr = W_hh + (size_t)(j * 128 + wv * 16 + l15) * H_ + quad * 8;
#pragma unroll
        for (int kt = 0; kt < 6; ++kt) {
            const float4* wp = (const float4*)(wr + kt * 32);
            float4 w0 = wp[0];
            float4 w1 = wp[1];
            f16x8 f = (f16x8){
                (_Float16)w0.x, (_Float16)w0.y, (_Float16)w0.z, (_Float16)w0.w,
                (_Float16)w1.x, (_Float16)w1.y, (_Float16)w1.z, (_Float16)w1.w};
            if (kt < 2)
                *(f16x8*)&wlds[wv][j][kt][(size_t)l * 8] = f;
            else
                wreg[j][kt - 2] = f;
        }
    }

    // per-lane epilogue mapping: 2 gate-sets.
    const int p     = quad >> 1;               // gate half 0/1
    const int rloc0 = (quad & 1) * 2;          // local rows rloc0, rloc0+1
    const int u     = wv * 16 + l15 + p * 128; // hidden unit
    const int grow0 = stripe * 4 + rloc0;      // global batch rows
    float c2[2] = {0.f, 0.f};

    // bounce addressing: 160 B per (wv,l15) row, 8 slots of 16 B,
    // 3-bit XOR swizzle -> writes/reads ~2-way (free).
    char* scb = (char*)&sc[wv][l15][0];
    const int swz = (l15 & 7) << 4;

    // x prefetch: 1 step ahead only.
    int xv[2];
#pragma unroll
    for (int rr = 0; rr < 2; ++rr) xv[rr] = x[(size_t)(grow0 + rr) * S_ + 0];

    __syncthreads();   // wlds + zbuf visible

    for (int s = 0; s < S_; ++s) {
        // T2h gather for THIS step (consumed in epilogue; MFMA covers latency)
        f16x4 tcv[2];
#pragma unroll
        for (int rr = 0; rr < 2; ++rr)
            tcv[rr] = *(const f16x4*)(T2h + ((size_t)xv[rr] * 256 + u) * 4);
        // x for next step
        if (s + 1 < S_) {
#pragma unroll
            for (int rr = 0; rr < 2; ++rr)
                xv[rr] = x[(size_t)(grow0 + rr) * S_ + s + 1];
        }

        // A-frag base: real rows for lanes l15<4, zero block otherwise.
        const _Float16* ha = (l15 < 4)
            ? (&hbuf[(s - 1) & 1][l15][0] + quad * 8)
            : (zbuf + quad * 8);

        // ---- two MFMA passes, bounce writes deferred-read: ONE stall/step.
#pragma unroll
        for (int pass = 0; pass < 2; ++pass) {
            // stream kt 6..7 frags for this pass's j's (coalesced 16B/lane;
            // resolved after the 24 resident MFMAs -> L2 latency covered)
            f16x8 wstr[4][2];
#pragma unroll
            for (int jj = 0; jj < 4; ++jj)
#pragma unroll
                for (int ktS = 0; ktS < 2; ++ktS)
                    wstr[jj][ktS] = *(const f16x8*)(
                        Wpk + ((size_t)((ktS * 8 + pass * 4 + jj) * 512 + tid)) * 8);

            f32x4 acc[4];
#pragma unroll
            for (int jj = 0; jj < 4; ++jj) acc[jj] = (f32x4){0.f, 0.f, 0.f, 0.f};

            if (s > 0) {
#pragma unroll
                for (int kt = 0; kt < 8; ++kt) {
                    f16x8 a = *(const f16x8*)(ha + kt * 32);
                    if (kt < 2) {
#pragma unroll
                        for (int jj = 0; jj < 4; ++jj) {
                            f16x8 b = *(const f16x8*)
                                &wlds[wv][pass * 4 + jj][kt][(size_t)l * 8];
                            acc[jj] = __builtin_amdgcn_mfma_f32_16x16x32_f16(
                                a, b, acc[jj], 0, 0, 0);
                        }
                    } else if (kt < 6) {
#pragma unroll
                        for (int jj = 0; jj < 4; ++jj)
                            acc[jj] = __builtin_amdgcn_mfma_f32_16x16x32_f16(
                                a, wreg[pass * 4 + jj][kt - 2], acc[jj], 0, 0, 0);
                    } else {
#pragma unroll
                        for (int jj = 0; jj < 4; ++jj)
                            acc[jj] = __builtin_amdgcn_mfma_f32_16x16x32_f16(
                                a, wstr[jj][kt - 6], acc[jj], 0, 0, 0);
                    }
                }
            }

            // bounce write: quad0 holds the 4 real C-rows (C/D row=quad*4+r);
            // slot = pass*4 + jj, 16 B each, XOR-swizzled.
            if (quad == 0) {
#pragma unroll
                for (int jj = 0; jj < 4; ++jj)
                    *(f32x4*)(scb + (((pass * 4 + jj) * 16) ^ swz)) = acc[jj];
            }
        }

        // single wait: all 8 slot-writes (and everything older) done.
        asm volatile("s_waitcnt lgkmcnt(0)" ::: "memory");

        // bounce read: gate t lives in slot j = 2t+p; rows rloc0,rloc0+1
        // are adjacent floats -> one b64 read per gate.
        float g[2][4];
#pragma unroll
        for (int t = 0; t < 4; ++t) {
            const int j = 2 * t + p;
            f32x2 gv = *(const f32x2*)(scb + ((j * 16) ^ swz) + rloc0 * 4);
            g[0][t] = gv[0];
            g[1][t] = gv[1];
        }

        // ---- epilogue: 2 gate-sets per lane
        const bool last = (s == S_ - 1);
#pragma unroll
        for (int rr = 0; rr < 2; ++rr) {
            float gi = sig_fast (g[rr][0] + (float)tcv[rr][0]);
            float gf = sig_fast (g[rr][1] + (float)tcv[rr][1]);
            float gg = tanh_fast(g[rr][2] + (float)tcv[rr][2]);
            float go = sig_fast (g[rr][3] + (float)tcv[rr][3]);
            float cc = gf * c2[rr] + gi * gg;
            c2[rr] = cc;
            float hv = go * tanh_fast(cc);
            if (!last) {
                hbuf[s & 1][rloc0 + rr][u] = (_Float16)hv;
            } else {
                hlast[(size_t)(grow0 + rr) * H_ + u] = hv;
            }
        }

        // one barrier per step: h_s visible to all waves' A-reads at s+1,
        // and hbuf[(s+1)&1] readers (step s) done before step s+1 overwrites.
        __syncthreads();
    }
}

// ---------------------------------------------------------------- K3: head
__global__ void out_kernel(const float* __restrict__ hlast,
                           const float* __restrict__ W_out,
                           const float* __restrict__ b_out,
                           float* __restrict__ out) {
    const int b = blockIdx.x;    // 256
    const int o = threadIdx.x;   // 128
    __shared__ float hl[H_];
    hl[o]       = hlast[b * H_ + o];
    hl[o + 128] = hlast[b * H_ + o + 128];
    __syncthreads();
    const float4* wp = (const float4*)(W_out + o * H_);
    float acc = 0.f;
#pragma unroll
    for (int i = 0; i < H_ / 4; ++i) {
        float4 w = wp[i];
        acc += w.x * hl[4*i] + w.y * hl[4*i+1] + w.z * hl[4*i+2] + w.w * hl[4*i+3];
    }
    out[b * O_ + o] = acc + b_out[o];
}

// ----------------------------------------------------------------- launcher
extern "C" void kernel_launch(void* const* d_in, const int* in_sizes, int n_in,
                              void* d_out, int out_size, void* d_ws, size_t ws_size,
                              hipStream_t stream) {
    const int*   x     = (const int*)  d_in[0];
    const float* emb   = (const float*)d_in[1];
    const float* W_ih  = (const float*)d_in[2];
    const float* W_hh  = (const float*)d_in[3];
    const float* b_ih  = (const float*)d_in[4];
    const float* b_hh  = (const float*)d_in[5];
    const float* W_out = (const float*)d_in[6];
    const float* b_out = (const float*)d_in[7];
    float* out = (float*)d_out;

    char* ws = (char*)d_ws;
    _Float16* T2h   = (_Float16*)(ws + T_OFF);
    float*    hlast = (float*)(ws + HLAST_OFF);
    _Float16* Wpk   = (_Float16*)(ws + WPK_OFF);

    build_table<<<dim3(V_), dim3(256), 0, stream>>>(emb, W_ih, b_ih, b_hh, T2h);
    prepack<<<dim3(16), dim3(512), 0, stream>>>(W_hh, Wpk);
    lstm_persistent<<<dim3(64), dim3(512), 0, stream>>>(x, W_hh, T2h, Wpk, hlast);
    out_kernel<<<dim3(B_), dim3(O_), 0, stream>>>(hlast, W_out, b_out, out);
}

// Round 7
// 915.818 us; speedup vs baseline: 1.8070x; 1.8070x over previous
//
#include <hip/hip_runtime.h>

// CharNNClassifier: out = (LSTM(emb[x]) last h) @ W_out^T + b_out
// B=256 S=512 V=256 E=128 H=256 4H=1024 O=128, fp32 in/out.
//
// R10: bounce eliminated by A-row placement.
//  R9 post-mortem: deferred bounce serialized the step (+2600 cyc) ->
//  reverted. R8 budget/SIMD-step: MFMA 2484 (floor), VALU 1455,
//  conflicts 500, idle 800 -> the bounce apparatus is the overhead.
//  R10 trick: C/D layout is row=(lane>>4)*4+reg. Place batch row rb at
//  A row 4*rb (rows {0,4,8,12} real, rest zero). Then C row 4*quad =
//  reg 0 of EVERY lane: acc[j][0], j=0..7 gives each lane its 2 complete
//  gate-sets (units wv*16+l15, +128; batch row = quad) IN REGISTERS.
//  No LDS bounce, no lgkmcnt drains, no sc buffer. Epilogue reads
//  acc[2t+p][0] directly; c-state c2[2] per lane (row quad).
//  Kept (proven): kt0..1 in LDS wlds, kt2..5 in wreg (128 VGPR),
//  kt6..7 streamed per pass from prepacked Wpk (no-spill split);
//  HSTRIDE 272 (R9's conflict fix); x/T2h 1-step prefetch; one
//  __syncthreads per step.
//  LDS = 128K wlds + 4.25K hbuf + 0.5K zbuf = 132.75 KB.
//  Regs ~ wreg 128 + acc 32 + wstr 32 + misc ~30 = ~222 <= 256.

typedef _Float16 f16x8 __attribute__((ext_vector_type(8)));
typedef _Float16 f16x4 __attribute__((ext_vector_type(4)));
typedef float    f32x4 __attribute__((ext_vector_type(4)));

#define B_  256
#define S_  512
#define V_  256
#define E_  128
#define H_  256
#define O_  128

// ws layout (bytes)
#define T_OFF     0u              // T2h: 256*256*4 fp16 = 512 KiB
#define HLAST_OFF (512u << 10)    // hlast: 256*256*4B   = 256 KiB
#define WPK_OFF   (768u << 10)    // Wpk: 16*512*16B     = 128 KiB

// ---------------------------------------------------------------- K1: table
// T2h[v][unit] = fp16x4 {i,f,g,o} pre-activations from the embedding path.
__global__ void build_table(const float* __restrict__ emb,
                            const float* __restrict__ W_ih,
                            const float* __restrict__ b_ih,
                            const float* __restrict__ b_hh,
                            _Float16* __restrict__ T2h) {
    const int v   = blockIdx.x;   // vocab id
    const int tid = threadIdx.x;  // 256 threads = hidden unit

    __shared__ float e[E_];
    if (tid < E_) e[tid] = emb[v * E_ + tid];
    __syncthreads();

    f16x4 tv;
#pragma unroll
    for (int t = 0; t < 4; ++t) {
        const int g = t * 256 + tid;
        const float4* wp = (const float4*)(W_ih + g * E_);
        float acc = 0.f;
#pragma unroll
        for (int i = 0; i < E_ / 4; ++i) {
            float4 w = wp[i];
            acc += w.x * e[4*i] + w.y * e[4*i+1] + w.z * e[4*i+2] + w.w * e[4*i+3];
        }
        tv[t] = (_Float16)(acc + b_ih[g] + b_hh[g]);
    }
    *(f16x4*)(T2h + ((size_t)v * 256 + tid) * 4) = tv;
}

// ------------------------------------------------------- K1b: W-frag prepack
// Wpk[blk=ktS*8+j][tid] = the f16x8 B-fragment thread tid needs for
// (kt = 6+ktS, j). Lane math mirrors the main kernel's prologue.
__global__ void prepack(const float* __restrict__ W_hh,
                        _Float16* __restrict__ Wpk) {
    const int blk = blockIdx.x;      // 0..15 = ktS*8 + j
    const int ktS = blk >> 3;
    const int j   = blk & 7;
    const int kt  = 6 + ktS;
    const int tid = threadIdx.x;     // 512
    const int wv = tid >> 6, l = tid & 63, l15 = l & 15, quad = l >> 4;
    const int n  = j * 128 + wv * 16 + l15;   // gate column
    const int k0 = kt * 32 + quad * 8;
    const float4* wp = (const float4*)(W_hh + (size_t)n * H_ + k0);
    float4 w0 = wp[0];
    float4 w1 = wp[1];
    f16x8 f = (f16x8){
        (_Float16)w0.x, (_Float16)w0.y, (_Float16)w0.z, (_Float16)w0.w,
        (_Float16)w1.x, (_Float16)w1.y, (_Float16)w1.z, (_Float16)w1.w};
    *(f16x8*)(Wpk + ((size_t)blk * 512 + tid) * 8) = f;
}

// ------------------------------------------------------------ K2: recurrence
// Pre-act bounds: |W_hh row . h| <= 256*(1/16) = 16 hard; |table| < ~5.
// Sigmoid needs no clamp; tanh keeps a +-30 clamp as overflow insurance.
__device__ __forceinline__ float sig_fast(float x) {
    float t = __builtin_amdgcn_exp2f(-1.4426950408889634f * x);
    return __builtin_amdgcn_rcpf(1.f + t);
}
__device__ __forceinline__ float tanh_fast(float x) {
    x = fminf(fmaxf(x, -30.f), 30.f);
    float t = __builtin_amdgcn_exp2f(-2.8853900817779268f * x);  // e^{-2x}
    return (1.f - t) * __builtin_amdgcn_rcpf(1.f + t);
}

#define HSTRIDE 272   // fp16/row: 544 B => row bank-phase 0/8/16/24

__launch_bounds__(512, 2)
__global__ void lstm_persistent(const int* __restrict__ x,
                                const float* __restrict__ W_hh,
                                const _Float16* __restrict__ T2h,
                                const _Float16* __restrict__ Wpk,
                                float* __restrict__ hlast) {
    const int tid    = threadIdx.x;
    const int wv     = tid >> 6;     // wave 0..7
    const int l      = tid & 63;
    const int l15    = l & 15;
    const int quad   = l >> 4;       // 0..3  == this lane's batch row (local)
    const int stripe = blockIdx.x;   // batch rows [stripe*4, +4)
    const int uu     = wv * 16 + l15;    // unit (p=0 half)

    // LDS: 128 KB weights (kt 0..1) + 4-row h dbuf + zero block.
    __shared__ __align__(16) _Float16 wlds[8][8][2][512];   // 128 KiB
    __shared__ __align__(16) _Float16 hbuf[2][4][HSTRIDE];  // 4.25 KiB
    __shared__ __align__(16) _Float16 zbuf[256];            // 512 B zeros

    if (tid < 128) ((int*)zbuf)[tid] = 0;

    // ---- prologue: kt 0..5 of W_hh -> fp16 B-frags (kt 0..1 LDS, 2..5 reg)
    // col n = j*128 + wv*16 + l15; k = kt*32 + quad*8 + i; B[k][n] = W_hh[n][k]
    f16x8 wreg[8][4];
#pragma unroll
    for (int j = 0; j < 8; ++j) {
        const float* wr = W_hh + (size_t)(j * 128 + uu) * H_ + quad * 8;
#pragma unroll
        for (int kt = 0; kt < 6; ++kt) {
            const float4* wp = (const float4*)(wr + kt * 32);
            float4 w0 = wp[0];
            float4 w1 = wp[1];
            f16x8 f = (f16x8){
                (_Float16)w0.x, (_Float16)w0.y, (_Float16)w0.z, (_Float16)w0.w,
                (_Float16)w1.x, (_Float16)w1.y, (_Float16)w1.z, (_Float16)w1.w};
            if (kt < 2)
                *(f16x8*)&wlds[wv][j][kt][(size_t)l * 8] = f;
            else
                wreg[j][kt - 2] = f;
        }
    }

    const int grow = stripe * 4 + quad;   // this lane's global batch row
    float c2[2] = {0.f, 0.f};             // c[row=quad][uu], c[row=quad][uu+128]

    // x prefetch: 1 step ahead (one row per lane = quad).
    int xv = x[(size_t)grow * S_];

    __syncthreads();   // wlds + zbuf visible

    for (int s = 0; s < S_; ++s) {
        // T2h gather for THIS step (consumed in epilogue; MFMAs cover latency)
        f16x4 tcv[2];
        tcv[0] = *(const f16x4*)(T2h + ((size_t)xv * 256 + uu) * 4);
        tcv[1] = *(const f16x4*)(T2h + ((size_t)xv * 256 + uu + 128) * 4);
        if (s + 1 < S_) xv = x[(size_t)grow * S_ + s + 1];

        f32x4 acc[8];
#pragma unroll
        for (int j = 0; j < 8; ++j) acc[j] = (f32x4){0.f, 0.f, 0.f, 0.f};

        if (s > 0) {
            // A row m = l15; real rows m in {0,4,8,12} hold batch row m/4,
            // all other rows read the zero block. k = kt*32 + quad*8 + i.
            const _Float16* ha = ((l15 & 3) == 0)
                ? (&hbuf[(s - 1) & 1][l15 >> 2][0] + quad * 8)
                : (zbuf + quad * 8);

            // two passes only to bound wstr register pressure (kt 6..7
            // streamed per pass from Wpk, coalesced 16B/lane, resolved
            // after the 24 resident MFMAs of the pass).
#pragma unroll
            for (int pass = 0; pass < 2; ++pass) {
                f16x8 wstr[4][2];
#pragma unroll
                for (int jj = 0; jj < 4; ++jj)
#pragma unroll
                    for (int ktS = 0; ktS < 2; ++ktS)
                        wstr[jj][ktS] = *(const f16x8*)(
                            Wpk + ((size_t)((ktS * 8 + pass * 4 + jj) * 512 + tid)) * 8);

#pragma unroll
                for (int kt = 0; kt < 8; ++kt) {
                    f16x8 a = *(const f16x8*)(ha + kt * 32);
                    if (kt < 2) {
#pragma unroll
                        for (int jj = 0; jj < 4; ++jj) {
                            f16x8 b = *(const f16x8*)
                                &wlds[wv][pass * 4 + jj][kt][(size_t)l * 8];
                            acc[pass * 4 + jj] =
                                __builtin_amdgcn_mfma_f32_16x16x32_f16(
                                    a, b, acc[pass * 4 + jj], 0, 0, 0);
                        }
                    } else if (kt < 6) {
#pragma unroll
                        for (int jj = 0; jj < 4; ++jj)
                            acc[pass * 4 + jj] =
                                __builtin_amdgcn_mfma_f32_16x16x32_f16(
                                    a, wreg[pass * 4 + jj][kt - 2],
                                    acc[pass * 4 + jj], 0, 0, 0);
                    } else {
#pragma unroll
                        for (int jj = 0; jj < 4; ++jj)
                            acc[pass * 4 + jj] =
                                __builtin_amdgcn_mfma_f32_16x16x32_f16(
                                    a, wstr[jj][kt - 6],
                                    acc[pass * 4 + jj], 0, 0, 0);
                    }
                }
            }
        }

        // ---- epilogue straight from registers: gate t of unit half p is
        // acc[2t+p][0] (C row 4*quad = reg 0 of this lane).
        const bool last = (s == S_ - 1);
#pragma unroll
        for (int p = 0; p < 2; ++p) {
            float gi = sig_fast (acc[0 + p][0] + (float)tcv[p][0]);
            float gf = sig_fast (acc[2 + p][0] + (float)tcv[p][1]);
            float gg = tanh_fast(acc[4 + p][0] + (float)tcv[p][2]);
            float go = sig_fast (acc[6 + p][0] + (float)tcv[p][3]);
            float cc = gf * c2[p] + gi * gg;
            c2[p] = cc;
            float hv = go * tanh_fast(cc);
            if (!last) {
                hbuf[s & 1][quad][uu + p * 128] = (_Float16)hv;
            } else {
                hlast[(size_t)grow * H_ + uu + p * 128] = hv;
            }
        }

        // one barrier per step: h_s (all waves' units) visible to all
        // A-reads at s+1; buffer s&1 readers done before s+2 overwrites.
        __syncthreads();
    }
}

// ---------------------------------------------------------------- K3: head
__global__ void out_kernel(const float* __restrict__ hlast,
                           const float* __restrict__ W_out,
                           const float* __restrict__ b_out,
                           float* __restrict__ out) {
    const int b = blockIdx.x;    // 256
    const int o = threadIdx.x;   // 128
    __shared__ float hl[H_];
    hl[o]       = hlast[b * H_ + o];
    hl[o + 128] = hlast[b * H_ + o + 128];
    __syncthreads();
    const float4* wp = (const float4*)(W_out + o * H_);
    float acc = 0.f;
#pragma unroll
    for (int i = 0; i < H_ / 4; ++i) {
        float4 w = wp[i];
        acc += w.x * hl[4*i] + w.y * hl[4*i+1] + w.z * hl[4*i+2] + w.w * hl[4*i+3];
    }
    out[b * O_ + o] = acc + b_out[o];
}

// ----------------------------------------------------------------- launcher
extern "C" void kernel_launch(void* const* d_in, const int* in_sizes, int n_in,
                              void* d_out, int out_size, void* d_ws, size_t ws_size,
                              hipStream_t stream) {
    const int*   x     = (const int*)  d_in[0];
    const float* emb   = (const float*)d_in[1];
    const float* W_ih  = (const float*)d_in[2];
    const float* W_hh  = (const float*)d_in[3];
    const float* b_ih  = (const float*)d_in[4];
    const float* b_hh  = (const float*)d_in[5];
    const float* W_out = (const float*)d_in[6];
    const float* b_out = (const float*)d_in[7];
    float* out = (float*)d_out;

    char* ws = (char*)d_ws;
    _Float16* T2h   = (_Float16*)(ws + T_OFF);
    float*    hlast = (float*)(ws + HLAST_OFF);
    _Float16* Wpk   = (_Float16*)(ws + WPK_OFF);

    build_table<<<dim3(V_), dim3(256), 0, stream>>>(emb, W_ih, b_ih, b_hh, T2h);
    prepack<<<dim3(16), dim3(512), 0, stream>>>(W_hh, Wpk);
    lstm_persistent<<<dim3(64), dim3(512), 0, stream>>>(x, W_hh, T2h, Wpk, hlast);
    out_kernel<<<dim3(B_), dim3(O_), 0, stream>>>(hlast, W_out, b_out, out);
}